// Round 22
// baseline (33.551 us; speedup 1.0000x reference)
//
#include <hip/hip_runtime.h>
#include <math.h>

// HPSS fused — packed fp16 dual-tile, 512-thread / FT=64 blocks.
// S (2,1,1025,2048) fp32. harm = median_31 along T (zero pad), perc = along F.
// outH = S*h^2/(h^2+p^2), outP = S - outH   (softmask Z cancels; sum = S).
//
// r21 model: static issue 11.3us, invariant ~20us stall floor, wave duty ~9%
// at 4 waves/SIMD. This round targets the stall floor:
//  - FT=64 x (2x64 t) tiles, 512 threads (8 waves): halo ratio 94/64 = 1.47
//    (was 1.94) -> staging/output -25%; LDS 53.1KB -> 3 blocks/CU =
//    24 waves/CU = 6 waves/SIMD (was ~4): +50% latency-hiding capacity.
//  - NO restrictive launch_bounds (cap-detonations r18/r19; natural packed
//    alloc ran 64-80). If alloc <=85 VGPR -> full 3 blocks; else 2 (neutral).
//  - outP = sv - outH (saves mul+cvt; NaN case: sv-NaN=NaN matches ref 0/0;
//    p2=0 case: outP ~ sv*2^-23 vs ref 0 — far under threshold).
//  - block-uniform f-guard fast path; s_setprio(1) around sort+slide (T5).
// Core per r21: tiles staged interleaved as half2 (cvt_pkrtz, monotone =>
// median commutes); sort/slide on v_pk_min/max_f16; slide delete = packed
// sub/shr/bfi select, insert = pk_min(pk_max(.)) med3; Batcher-32 pruned.

#define DIM_T 2048
#define DIM_F 1025
#define HALF 15
#define FT 64            // output f-rows per block
#define TT 64            // output t-cols per tile (x2 tiles packed)
#define RW 8             // outputs per thread along sliding axis
#define NTHR 512
#define TROWS (FT + 30)  // 94 staged rows
#define VPR 24           // float4 vecs per row (96 cols, [t0-16, t0+80))
#define TSTR 97          // h16x2 elements (dwords); odd -> conflict-free
#define HSTR 65          // hl stride in dwords (odd)
#define NVEC (TROWS * VPR)   // 2256
#define FEED (RW + 30)   // 38

typedef _Float16 h16;
typedef _Float16 h16x2 __attribute__((ext_vector_type(2)));
typedef __fp16 fp16x2 __attribute__((ext_vector_type(2)));
typedef short short2v __attribute__((ext_vector_type(2)));

union pku { h16x2 h; fp16x2 f; unsigned int u; short2v s; };

__device__ __forceinline__ h16x2 pmin(h16x2 a, h16x2 b) {
#if __has_builtin(__builtin_elementwise_min)
    return __builtin_elementwise_min(a, b);
#else
    h16x2 r; r.x = a.x < b.x ? a.x : b.x; r.y = a.y < b.y ? a.y : b.y; return r;
#endif
}
__device__ __forceinline__ h16x2 pmax(h16x2 a, h16x2 b) {
#if __has_builtin(__builtin_elementwise_max)
    return __builtin_elementwise_max(a, b);
#else
    h16x2 r; r.x = a.x > b.x ? a.x : b.x; r.y = a.y > b.y ? a.y : b.y; return r;
#endif
}

__device__ __forceinline__ void ce(h16x2& a, h16x2& b) {
    const h16x2 mn = pmin(a, b);
    b = pmax(a, b);
    a = mn;
}

// Batcher-32, CEs touching index 31 pruned (w[31] = +INF pair is inert).
__device__ __forceinline__ void sort32(h16x2 (&a)[32]) {
#pragma unroll
    for (int p = 1; p < 32; p <<= 1) {
#pragma unroll
        for (int k = p; k >= 1; k >>= 1) {
#pragma unroll
            for (int j = k & (p - 1); j + k < 32; j += 2 * k) {
#pragma unroll
                for (int i = 0; i < k; ++i) {
                    if (i + j + k < 31) {
                        if ((i + j) / (2 * p) == (i + j + k) / (2 * p)) {
                            ce(a[i + j], a[i + j + k]);
                        }
                    }
                }
            }
        }
    }
}

// packed sorted-window slide: per half, remove xo (present in w[0..30]),
// insert xn. w[31] = +INF pair, preserved.
__device__ __forceinline__ void slide(h16x2 (&w)[32], h16x2 xo, h16x2 xn) {
    pku m0, a0, b0, D0;
    m0.h = w[0] - xo;
    m0.s = m0.s >> 15;                        // ones where w<xo
    a0.h = w[0]; b0.h = w[1];
    D0.u = (a0.u & m0.u) | (b0.u & ~m0.u);    // v_bfi_b32
    h16x2 dprev = D0.h;
    h16x2 rprev = pmin(xn, dprev);
#pragma unroll
    for (int i = 1; i < 31; ++i) {
        pku mi, ai, bi, Di;
        mi.h = w[i] - xo;
        mi.s = mi.s >> 15;
        ai.h = w[i]; bi.h = w[i + 1];
        Di.u = (ai.u & mi.u) | (bi.u & ~mi.u);
        const h16x2 ri = pmin(pmax(dprev, xn), Di.h);  // med3 (D sorted)
        w[i - 1] = rprev;
        dprev = Di.h;
        rprev = ri;
    }
    w[30] = rprev;
}

// load one staging float4 for tile at t0x (vec index li)
__device__ __forceinline__ float4 load_vec(const float* __restrict__ Sb,
                                           int f0, int t0x, int li) {
    float4 v = make_float4(0.f, 0.f, 0.f, 0.f);
    if (li < NVEC) {
        const int row = li / VPR;
        const int pos = li - row * VPR;
        const int f  = f0 - HALF + row;
        const int tg = t0x - 16 + pos * 4;
        if ((unsigned)f < (unsigned)DIM_F && (unsigned)tg <= (unsigned)(DIM_T - 4))
            v = *(const float4*)&Sb[(size_t)f * DIM_T + tg];
    }
    return v;
}

__device__ __forceinline__ h16x2 pack2(float a, float b) {
    pku t;
    t.f = __builtin_amdgcn_cvt_pkrtz(a, b);  // RTZ, monotone
    return t.h;
}

// write interleaved pack(A,B) as 4 dwords
__device__ __forceinline__ void write_vec_pk(h16x2* __restrict__ tile, int li,
                                             float4 a, float4 b) {
    if (li < NVEC) {
        const int row = li / VPR;
        const int pos = li - row * VPR;
        h16x2* p = &tile[row * TSTR + pos * 4];
        p[0] = pack2(a.x, b.x);
        p[1] = pack2(a.y, b.y);
        p[2] = pack2(a.z, b.z);
        p[3] = pack2(a.w, b.w);
    }
}

__global__ void hpss_fused(const float* __restrict__ S,
                           float* __restrict__ outH,
                           float* __restrict__ outP) {
    __shared__ h16x2 tile[TROWS * TSTR];  // 36472 B (packed A|B)
    __shared__ h16x2 hl[FT * HSTR];       // 16640 B (packed harm A|B)

    const int tid = threadIdx.x;
    const int t0A = blockIdx.x * (2 * TT);      // tile A cols
    const int t0B = t0A + TT;                   // tile B cols
    const int f0  = blockIdx.y * FT;
    const int b   = blockIdx.z;
    const float* __restrict__ Sb = S + (size_t)b * DIM_F * DIM_T;

    // ---- stage both tiles interleaved as half2, coalesced ----
#pragma unroll
    for (int it = 0; it < (NVEC + NTHR - 1) / NTHR; ++it) {   // 5 iters
        const int li = it * NTHR + tid;
        const float4 vA = load_vec(Sb, f0, t0A, li);
        const float4 vB = load_vec(Sb, f0, t0B, li);
        write_vec_pk(tile, li, vA, vB);
    }
    __syncthreads();

    pku inf; inf.u = 0x7C007C00u;   // +INF | +INF

    // ---- phase H: packed harmonic medians (slide along t) -> hl ----
    {
        const int fl = tid & 63;          // output f row 0..63
        const int tb = (tid >> 6) * RW;   // t chunk base 0..56
        const h16x2* lr = tile + (fl + HALF) * TSTR + tb + 1;

        h16x2 r[FEED];
#pragma unroll
        for (int d = 0; d < FEED; ++d) r[d] = lr[d];

        h16x2 w[32];
        w[31] = inf.h;
#pragma unroll
        for (int d = 0; d < 31; ++d) w[d] = r[d];
        __builtin_amdgcn_s_setprio(1);
        sort32(w);
#pragma unroll
        for (int s = 0; s < RW; ++s) {
            hl[fl * HSTR + tb + s] = w[15];
            if (s < RW - 1) slide(w, r[s], r[s + 31]);
        }
        __builtin_amdgcn_s_setprio(0);
    }
    __syncthreads();

    // ---- phase P: packed percussive medians + combine + store ----
    {
        const int lane = tid & 63;        // t within tile
        const int fb   = (tid >> 6) * RW; // f chunk base 0..56

        h16x2 r[FEED];
#pragma unroll
        for (int d = 0; d < FEED; ++d) r[d] = tile[(fb + d) * TSTR + 16 + lane];
        h16x2 hp[RW];
#pragma unroll
        for (int s = 0; s < RW; ++s) hp[s] = hl[(fb + s) * HSTR + lane];

        h16x2 w[32];
        w[31] = inf.h;
        __builtin_amdgcn_s_setprio(1);
#pragma unroll
        for (int d = 0; d < 31; ++d) w[d] = r[d];
        sort32(w);
        __builtin_amdgcn_s_setprio(0);

        const bool fullF = (f0 + FT <= DIM_F);   // block-uniform
#pragma unroll
        for (int s = 0; s < RW; ++s) {
            const int f = f0 + fb + s;
            if (fullF || f < DIM_F) {
                const h16x2 pc = w[15], hm = hp[s], sv = r[s + 15];
                // tile A (lo half)
                {
                    const float harm = (float)hm.x, perc = (float)pc.x;
                    const float h2 = harm * harm, p2 = perc * perc;
                    const float inv = __builtin_amdgcn_rcpf(h2 + p2); // 0->INF; 0*INF=NaN matches ref
                    const float svf = (float)sv.x;
                    const float hv  = svf * h2 * inv;
                    const size_t oi = ((size_t)b * DIM_F + f) * DIM_T + (t0A + lane);
                    outH[oi] = hv;
                    outP[oi] = svf - hv;
                }
                // tile B (hi half)
                {
                    const float harm = (float)hm.y, perc = (float)pc.y;
                    const float h2 = harm * harm, p2 = perc * perc;
                    const float inv = __builtin_amdgcn_rcpf(h2 + p2);
                    const float svf = (float)sv.y;
                    const float hv  = svf * h2 * inv;
                    const size_t oi = ((size_t)b * DIM_F + f) * DIM_T + (t0B + lane);
                    outH[oi] = hv;
                    outP[oi] = svf - hv;
                }
            }
            if (s < RW - 1) {
                __builtin_amdgcn_s_setprio(1);
                slide(w, r[s], r[s + 31]);
                __builtin_amdgcn_s_setprio(0);
            }
        }
    }
}

extern "C" void kernel_launch(void* const* d_in, const int* in_sizes, int n_in,
                              void* d_out, int out_size, void* d_ws, size_t ws_size,
                              hipStream_t stream) {
    const float* S = (const float*)d_in[0];
    float* outH = (float*)d_out;
    float* outP = outH + (size_t)2 * DIM_F * DIM_T;

    dim3 grid(DIM_T / (2 * TT), (DIM_F + FT - 1) / FT, 2);  // 16 x 17 x 2 = 544
    hpss_fused<<<grid, NTHR, 0, stream>>>(S, outH, outP);
}

// Round 23
// 32.129 us; speedup vs baseline: 1.0443x; 1.0443x over previous
//
#include <hip/hip_runtime.h>
#include <math.h>

// HPSS fused — PACKED fp16 dual-tile edition (r21 verbatim; best: 31.97us).
// S (2,1,1025,2048) fp32. harm = median_31 along T (zero pad), perc = along F.
// outH = S*h^2/(h^2+p^2), outP = S*p^2/(h^2+p^2)   (softmask Z cancels).
//
// Two adjacent 32(f)x64(t) tiles (A,B) staged INTERLEAVED as half2:
// tile[row][col] = pack(fp16(A), fp16(B)). Every ds_read_b32 feeds both
// tiles; sort/slide run on v_pk_min/max_f16 (1 CE = 2 ops for 2 windows).
// Slide delete is VCC-free bitwise select:
//   m = (short2)(w[i]-xo) >> 15; D[i] = (w[i]&m) | (w[i+1]&~m)   (v_bfi)
// insert: w'[i] = pk_min(pk_max(D[i-1], xn), D[i]) (D sorted => med3).
// Numerics: fp16 container (cvt_pkrtz RTZ is monotone => median commutes);
// absmax pinned at 0.0039 vs 2e-2 threshold across all fp16 rounds.
//
// Final ledger (r13-r22): packing -3.3us, T14 -3.5us (superseded), all other
// structural probes (barrier removal, op-prune, occupancy caps/geometry,
// noinline/loop code-size) null or regressive. Remaining dur ~= latency/issue
// floor: VALU ~11us + HBM ~8us + LDS ~4.5us, imperfectly overlapped at
// 4-5 waves/SIMD; caps below natural VGPR demand detonate the allocator.

#define DIM_T 2048
#define DIM_F 1025
#define HALF 15
#define FT 32            // output f-rows per tile
#define TT 64            // output t-cols per tile (x2 tiles per block)
#define RW 8             // outputs per thread along sliding axis
#define TROWS (FT + 30)  // 62 staged rows
#define VPR 24           // float4 vecs per row (96 cols, [t0-16, t0+80))
#define TSTR 97          // h16x2 elements (dwords); odd -> conflict-free
#define HSTR 65          // hl stride in dwords (odd)
#define NVEC (TROWS * VPR)   // 1488
#define FEED (RW + 30)   // 38

typedef _Float16 h16;
typedef _Float16 h16x2 __attribute__((ext_vector_type(2)));
typedef __fp16 fp16x2 __attribute__((ext_vector_type(2)));
typedef short short2v __attribute__((ext_vector_type(2)));

union pku { h16x2 h; fp16x2 f; unsigned int u; short2v s; };

__device__ __forceinline__ h16x2 pmin(h16x2 a, h16x2 b) {
#if __has_builtin(__builtin_elementwise_min)
    return __builtin_elementwise_min(a, b);
#else
    h16x2 r; r.x = a.x < b.x ? a.x : b.x; r.y = a.y < b.y ? a.y : b.y; return r;
#endif
}
__device__ __forceinline__ h16x2 pmax(h16x2 a, h16x2 b) {
#if __has_builtin(__builtin_elementwise_max)
    return __builtin_elementwise_max(a, b);
#else
    h16x2 r; r.x = a.x > b.x ? a.x : b.x; r.y = a.y > b.y ? a.y : b.y; return r;
#endif
}

__device__ __forceinline__ void ce(h16x2& a, h16x2& b) {
    const h16x2 mn = pmin(a, b);
    b = pmax(a, b);
    a = mn;
}

// Batcher-32, CEs touching index 31 pruned (w[31] = +INF pair is inert).
__device__ __forceinline__ void sort32(h16x2 (&a)[32]) {
#pragma unroll
    for (int p = 1; p < 32; p <<= 1) {
#pragma unroll
        for (int k = p; k >= 1; k >>= 1) {
#pragma unroll
            for (int j = k & (p - 1); j + k < 32; j += 2 * k) {
#pragma unroll
                for (int i = 0; i < k; ++i) {
                    if (i + j + k < 31) {
                        if ((i + j) / (2 * p) == (i + j + k) / (2 * p)) {
                            ce(a[i + j], a[i + j + k]);
                        }
                    }
                }
            }
        }
    }
}

// packed sorted-window slide: per half, remove xo (present in w[0..30]),
// insert xn. w[31] = +INF pair, preserved.
__device__ __forceinline__ void slide(h16x2 (&w)[32], h16x2 xo, h16x2 xn) {
    pku m0, a0, b0, D0;
    m0.h = w[0] - xo;                 // packed sub — sign exact
    m0.s = m0.s >> 15;                // ones where w<xo
    a0.h = w[0]; b0.h = w[1];
    D0.u = (a0.u & m0.u) | (b0.u & ~m0.u);   // v_bfi_b32
    h16x2 dprev = D0.h;
    h16x2 rprev = pmin(xn, dprev);
#pragma unroll
    for (int i = 1; i < 31; ++i) {
        pku mi, ai, bi, Di;
        mi.h = w[i] - xo;
        mi.s = mi.s >> 15;
        ai.h = w[i]; bi.h = w[i + 1];
        Di.u = (ai.u & mi.u) | (bi.u & ~mi.u);
        const h16x2 ri = pmin(pmax(dprev, xn), Di.h);  // med3 (D sorted)
        w[i - 1] = rprev;
        dprev = Di.h;
        rprev = ri;
    }
    w[30] = rprev;
}

// load one staging float4 for tile at t0x (vec index li)
__device__ __forceinline__ float4 load_vec(const float* __restrict__ Sb,
                                           int f0, int t0x, int li) {
    float4 v = make_float4(0.f, 0.f, 0.f, 0.f);
    if (li < NVEC) {
        const int row = li / VPR;
        const int pos = li - row * VPR;
        const int f  = f0 - HALF + row;
        const int tg = t0x - 16 + pos * 4;
        if ((unsigned)f < (unsigned)DIM_F && (unsigned)tg <= (unsigned)(DIM_T - 4))
            v = *(const float4*)&Sb[(size_t)f * DIM_T + tg];
    }
    return v;
}

__device__ __forceinline__ h16x2 pack2(float a, float b) {
    pku t;
    t.f = __builtin_amdgcn_cvt_pkrtz(a, b);  // RTZ, monotone
    return t.h;
}

// write interleaved pack(A,B) as 4 dwords
__device__ __forceinline__ void write_vec_pk(h16x2* __restrict__ tile, int li,
                                             float4 a, float4 b) {
    if (li < NVEC) {
        const int row = li / VPR;
        const int pos = li - row * VPR;
        h16x2* p = &tile[row * TSTR + pos * 4];
        p[0] = pack2(a.x, b.x);
        p[1] = pack2(a.y, b.y);
        p[2] = pack2(a.z, b.z);
        p[3] = pack2(a.w, b.w);
    }
}

__global__ __launch_bounds__(256, 4) void hpss_fused(const float* __restrict__ S,
                                                     float* __restrict__ outH,
                                                     float* __restrict__ outP) {
    __shared__ h16x2 tile[TROWS * TSTR];  // 24056 B (packed A|B)
    __shared__ h16x2 hl[FT * HSTR];       //  8320 B (packed harm A|B)

    const int tid = threadIdx.x;
    const int t0A = blockIdx.x * (2 * TT);      // tile A cols
    const int t0B = t0A + TT;                   // tile B cols
    const int f0  = blockIdx.y * FT;
    const int b   = blockIdx.z;
    const float* __restrict__ Sb = S + (size_t)b * DIM_F * DIM_T;

    // ---- stage both tiles interleaved as half2, coalesced ----
#pragma unroll
    for (int it = 0; it < 6; ++it) {
        const int li = it * 256 + tid;
        const float4 vA = load_vec(Sb, f0, t0A, li);
        const float4 vB = load_vec(Sb, f0, t0B, li);
        write_vec_pk(tile, li, vA, vB);
    }
    __syncthreads();

    pku inf; inf.u = 0x7C007C00u;   // +INF | +INF

    // ---- phase H: packed harmonic medians (slide along t) -> hl ----
    {
        const int fl = tid & 31;          // output f row 0..31
        const int tb = (tid >> 5) * RW;   // t chunk base 0..56
        const h16x2* lr = tile + (fl + HALF) * TSTR + tb + 1;

        h16x2 r[FEED];
#pragma unroll
        for (int d = 0; d < FEED; ++d) r[d] = lr[d];

        h16x2 w[32];
        w[31] = inf.h;
#pragma unroll
        for (int d = 0; d < 31; ++d) w[d] = r[d];
        sort32(w);
#pragma unroll
        for (int s = 0; s < RW; ++s) {
            hl[fl * HSTR + tb + s] = w[15];
            if (s < RW - 1) slide(w, r[s], r[s + 31]);
        }
    }
    __syncthreads();

    // ---- phase P: packed percussive medians + combine + store ----
    {
        const int lane = tid & 63;        // t within tile
        const int fb   = (tid >> 6) * RW; // f chunk base 0,8,16,24

        h16x2 r[FEED];
#pragma unroll
        for (int d = 0; d < FEED; ++d) r[d] = tile[(fb + d) * TSTR + 16 + lane];
        h16x2 hp[RW];
#pragma unroll
        for (int s = 0; s < RW; ++s) hp[s] = hl[(fb + s) * HSTR + lane];

        h16x2 w[32];
        w[31] = inf.h;
#pragma unroll
        for (int d = 0; d < 31; ++d) w[d] = r[d];
        sort32(w);
#pragma unroll
        for (int s = 0; s < RW; ++s) {
            const int f = f0 + fb + s;
            if (f < DIM_F) {
                const h16x2 pc = w[15], hm = hp[s], sv = r[s + 15];
                // tile A (lo half)
                {
                    const float harm = (float)hm.x, perc = (float)pc.x;
                    const float h2 = harm * harm, p2 = perc * perc;
                    const float inv = __builtin_amdgcn_rcpf(h2 + p2); // 0->INF; 0*INF=NaN matches ref
                    const size_t oi = ((size_t)b * DIM_F + f) * DIM_T + (t0A + lane);
                    outH[oi] = (float)sv.x * h2 * inv;
                    outP[oi] = (float)sv.x * p2 * inv;
                }
                // tile B (hi half)
                {
                    const float harm = (float)hm.y, perc = (float)pc.y;
                    const float h2 = harm * harm, p2 = perc * perc;
                    const float inv = __builtin_amdgcn_rcpf(h2 + p2);
                    const size_t oi = ((size_t)b * DIM_F + f) * DIM_T + (t0B + lane);
                    outH[oi] = (float)sv.y * h2 * inv;
                    outP[oi] = (float)sv.y * p2 * inv;
                }
            }
            if (s < RW - 1) slide(w, r[s], r[s + 31]);
        }
    }
}

extern "C" void kernel_launch(void* const* d_in, const int* in_sizes, int n_in,
                              void* d_out, int out_size, void* d_ws, size_t ws_size,
                              hipStream_t stream) {
    const float* S = (const float*)d_in[0];
    float* outH = (float*)d_out;
    float* outP = outH + (size_t)2 * DIM_F * DIM_T;

    dim3 grid(DIM_T / (2 * TT), (DIM_F + FT - 1) / FT, 2);  // 16 x 33 x 2 = 1056
    hpss_fused<<<grid, 256, 0, stream>>>(S, outH, outP);
}